// Round 4
// baseline (90.947 us; speedup 1.0000x reference)
//
#include <hip/hip_runtime.h>
#include <hip/hip_bf16.h>

#define N 8192
#define D 128
#define HALF_N 4096
// z pre-scaled by sqrt(10 * log2(e)) so acc = z.z^T is sim in log2 domain:
// exp(sim) == exp2(acc). pos (= sim) recovered as acc * ln2 on its single tile.
#define SQRT_SCALE_LOG2E 3.79828236f
#define LN2 0.693147180559945f

#define BLOCK_ROWS 256   // 4 waves * 64 rows each
#define COLS_PER_ITER 64
#define COL_SPLITS 16
#define COLS_PER_BLOCK (N / COL_SPLITS)          // 512
#define ITERS (COLS_PER_BLOCK / COLS_PER_ITER)   // 8
#define LDS_STRIDE 136   // 128 + 8 pad

typedef short frag8 __attribute__((ext_vector_type(8)));
typedef float f32x4 __attribute__((ext_vector_type(4)));

// ws layout (floats): pos[N] | psums[COL_SPLITS][N] | acc0 | counter | pad | z (bf16)
#define OFF_POS    0
#define OFF_PSUMS  (N)
#define OFF_ACC    (N + COL_SPLITS * N)
#define OFF_CNT    (OFF_ACC + 1)
#define OFF_Z_BYTES ((OFF_ACC + 64) * 4)

__device__ __forceinline__ unsigned short f2bf(float f) {
    unsigned int u = __float_as_uint(f);
    u += 0x7FFFu + ((u >> 16) & 1u);
    return (unsigned short)(u >> 16);
}

// K1: z = sqrt(10*log2e) * x / max(||x||, eps)  (bf16); zero acc0 + counter.
__global__ __launch_bounds__(256) void k_normalize(const float* __restrict__ x,
                                                   unsigned short* __restrict__ z,
                                                   float* __restrict__ acc0,
                                                   unsigned int* __restrict__ counter) {
    const int row  = blockIdx.x * 4 + (threadIdx.x >> 6);
    const int lane = threadIdx.x & 63;
    float2 v = ((const float2*)x)[row * 64 + lane];
    float s = v.x * v.x + v.y * v.y;
    #pragma unroll
    for (int m = 32; m >= 1; m >>= 1) s += __shfl_xor(s, m);
    float inv = SQRT_SCALE_LOG2E / fmaxf(sqrtf(s), 1e-8f);
    ushort2 o;
    o.x = f2bf(v.x * inv);
    o.y = f2bf(v.y * inv);
    ((ushort2*)z)[row * 64 + lane] = o;
    if (blockIdx.x == 0 && threadIdx.x == 0) { acc0[0] = 0.0f; counter[0] = 0u; }
}

// K2: fused z.z^T + exp2 + per-row partial sums, register-prefetched staging.
__global__ __launch_bounds__(256, 2) void k_simloss(const unsigned short* __restrict__ z,
                                                    float* __restrict__ psums,
                                                    float* __restrict__ pos) {
    __shared__ unsigned short lds[COLS_PER_ITER * LDS_STRIDE];  // 17408 B

    const int tid  = threadIdx.x;
    const int wave = tid >> 6;
    const int lane = tid & 63;
    const int l15  = lane & 15;
    const int quad = lane >> 4;
    const int wrow = blockIdx.x * BLOCK_ROWS + wave * 64;
    const int colbase0 = blockIdx.y * COLS_PER_BLOCK;
    const int posbase  = (wrow + HALF_N) & (N - 1);

    // Staging geometry: 1024 units of 8 bf16; this thread's unit per u-step.
    const int st_r  = tid >> 4;          // 0..15 within each 16-row group
    const int st_c8 = tid & 15;

    // A fragments: 4 row-stripes of 16 x K=128, register-resident (64 VGPRs).
    frag8 a[4][4];
    #pragma unroll
    for (int s = 0; s < 4; ++s) {
        const uint4* p = (const uint4*)&z[(wrow + s * 16 + l15) * D + quad * 8];
        #pragma unroll
        for (int q = 0; q < 4; ++q) {
            uint4 t = p[q * 4];
            a[s][q] = *(frag8*)&t;
        }
    }

    float sums[4][4];
    #pragma unroll
    for (int s = 0; s < 4; ++s)
        #pragma unroll
        for (int r = 0; r < 4; ++r) sums[s][r] = 0.0f;

    // Prefetch iteration 0's 64x128 bf16 tile into registers.
    uint4 t[4];
    #pragma unroll
    for (int u = 0; u < 4; ++u)
        t[u] = *(const uint4*)&z[(colbase0 + u * 16 + st_r) * D + st_c8 * 8];

    for (int it = 0; it < ITERS; ++it) {
        const int colbase = colbase0 + it * COLS_PER_ITER;
        __syncthreads();
        #pragma unroll
        for (int u = 0; u < 4; ++u)
            *(uint4*)&lds[(u * 16 + st_r) * LDS_STRIDE + st_c8 * 8] = t[u];
        __syncthreads();

        // Issue next tile's loads; latency hides under this iter's MFMA+exp.
        if (it + 1 < ITERS) {
            const int nb = colbase + COLS_PER_ITER;
            #pragma unroll
            for (int u = 0; u < 4; ++u)
                t[u] = *(const uint4*)&z[(nb + u * 16 + st_r) * D + st_c8 * 8];
        }

        const bool isDiag = (colbase == wrow);
        const bool isPos  = (colbase == posbase);
        const unsigned short* lp = &lds[l15 * LDS_STRIDE + quad * 8];

        #pragma unroll
        for (int c = 0; c < 4; ++c) {
            f32x4 acc[4];
            #pragma unroll
            for (int s = 0; s < 4; ++s) acc[s] = (f32x4){0.f, 0.f, 0.f, 0.f};
            #pragma unroll
            for (int q = 0; q < 4; ++q) {
                frag8 b = *(const frag8*)(lp + c * 16 * LDS_STRIDE + q * 32);
                #pragma unroll
                for (int s = 0; s < 4; ++s)
                    acc[s] = __builtin_amdgcn_mfma_f32_16x16x32_bf16(a[s][q], b, acc[s], 0, 0, 0);
            }
            if (isDiag | isPos) {
                // special tile: local diagonal element at c==s, l15==quad*4+r
                #pragma unroll
                for (int s = 0; s < 4; ++s)
                    #pragma unroll
                    for (int r = 0; r < 4; ++r) {
                        float v = acc[s][r];
                        float e = __builtin_amdgcn_exp2f(v);
                        if (c == s) {  // compile-time
                            bool hit = (l15 == quad * 4 + r);
                            if (isDiag && hit) e = 0.0f;
                            if (isPos  && hit) pos[wrow + s * 16 + quad * 4 + r] = v * LN2;
                        }
                        sums[s][r] += e;
                    }
            } else {
                #pragma unroll
                for (int s = 0; s < 4; ++s)
                    #pragma unroll
                    for (int r = 0; r < 4; ++r)
                        sums[s][r] += __builtin_amdgcn_exp2f(acc[s][r]);
            }
        }
    }

    // Reduce each row-sum across the 16 lanes holding that row; one store per row.
    #pragma unroll
    for (int s = 0; s < 4; ++s)
        #pragma unroll
        for (int r = 0; r < 4; ++r) {
            float v = sums[s][r];
            v += __shfl_xor(v, 1);
            v += __shfl_xor(v, 2);
            v += __shfl_xor(v, 4);
            v += __shfl_xor(v, 8);
            if (l15 == 0)
                psums[blockIdx.y * N + wrow + s * 16 + quad * 4 + r] = v;
        }
}

// K3: per-row loss = log(sum of partials) - pos; block-reduce; last block writes mean.
__global__ __launch_bounds__(256) void k_rowloss(const float* __restrict__ psums,
                                                 const float* __restrict__ pos,
                                                 float* __restrict__ acc0,
                                                 unsigned int* __restrict__ counter,
                                                 float* __restrict__ out) {
    const int row = blockIdx.x * 256 + threadIdx.x;
    float t = 0.0f;
    #pragma unroll
    for (int s = 0; s < COL_SPLITS; ++s) t += psums[s * N + row];
    float loss = __logf(t) - pos[row];
    #pragma unroll
    for (int m = 32; m >= 1; m >>= 1) loss += __shfl_xor(loss, m);
    __shared__ float p[4];
    if ((threadIdx.x & 63) == 0) p[threadIdx.x >> 6] = loss;
    __syncthreads();
    if (threadIdx.x == 0) {
        atomicAdd(acc0, p[0] + p[1] + p[2] + p[3]);
        __threadfence();
        unsigned prev = atomicAdd(counter, 1u);
        if (prev == gridDim.x - 1) {
            float total = atomicAdd(acc0, 0.0f);  // coherent read-back
            out[0] = total * (1.0f / N);
        }
    }
}

extern "C" void kernel_launch(void* const* d_in, const int* in_sizes, int n_in,
                              void* d_out, int out_size, void* d_ws, size_t ws_size,
                              hipStream_t stream) {
    const float* x = (const float*)d_in[0];
    float* wsf   = (float*)d_ws;
    float* pos   = wsf + OFF_POS;
    float* psums = wsf + OFF_PSUMS;
    float* acc0  = wsf + OFF_ACC;
    unsigned int* counter = (unsigned int*)(wsf + OFF_CNT);
    unsigned short* z = (unsigned short*)((char*)d_ws + OFF_Z_BYTES);

    k_normalize<<<N / 4, 256, 0, stream>>>(x, z, acc0, counter);
    dim3 g2(N / BLOCK_ROWS, COL_SPLITS);  // (32, 16) = 512 blocks -> 2/CU
    k_simloss<<<g2, 256, 0, stream>>>(z, psums, pos);
    k_rowloss<<<N / 256, 256, 0, stream>>>(psums, pos, acc0, counter, (float*)d_out);
}

// Round 5
// 85.597 us; speedup vs baseline: 1.0625x; 1.0625x over previous
//
#include <hip/hip_runtime.h>
#include <hip/hip_bf16.h>

#define N 8192
#define D 128
#define HALF_N 4096
// z pre-scaled by sqrt(10*log2e): acc = z.z^T is sim in log2 domain;
// exp(sim) == exp2(acc); sim recovered as acc*LN2 for the pos capture.
#define SQRT_SCALE_LOG2E 3.79828236f
#define LN2 0.693147180559945f

#define COLS_PER_ITER 64
#define ITERS 2          // 128 cols per block
#define LDS_STRIDE 136   // 64 rows x 128 K bf16, padded (perfect 8-pass b128 spread)

typedef short frag8 __attribute__((ext_vector_type(8)));
typedef float f32x4 __attribute__((ext_vector_type(4)));

// ws layout (floats): pos[N] | sumexp[N] | acc0 | cnt | pad | z (bf16)
#define OFF_POS 0
#define OFF_SUM N
#define OFF_ACC (2 * N)
#define OFF_CNT (2 * N + 1)
#define OFF_Z_BYTES ((2 * N + 64) * 4)   // 16B-aligned

__device__ __forceinline__ unsigned short f2bf(float f) {
    unsigned int u = __float_as_uint(f);
    u += 0x7FFFu + ((u >> 16) & 1u);
    return (unsigned short)(u >> 16);
}

// K1: z = sqrt(10*log2e) * x / max(||x||,eps) (bf16); zero sumexp/acc0/cnt.
__global__ __launch_bounds__(256) void k_normalize(const float* __restrict__ x,
                                                   unsigned short* __restrict__ z,
                                                   float* __restrict__ wsf) {
    const int row  = blockIdx.x * 4 + (threadIdx.x >> 6);
    const int lane = threadIdx.x & 63;
    float2 v = ((const float2*)x)[row * 64 + lane];
    float s = v.x * v.x + v.y * v.y;
    #pragma unroll
    for (int m = 32; m >= 1; m >>= 1) s += __shfl_xor(s, m);
    float inv = SQRT_SCALE_LOG2E / fmaxf(sqrtf(s), 1e-8f);
    ushort2 o;
    o.x = f2bf(v.x * inv);
    o.y = f2bf(v.y * inv);
    ((ushort2*)z)[row * 64 + lane] = o;
    const int gid = blockIdx.x * 256 + threadIdx.x;
    if (gid < N + 2) wsf[OFF_SUM + gid] = 0.0f;   // sumexp[N], acc0, cnt
}

// K2: upper-triangle z.z^T tiles + exp2; row-sums and mirrored col-sums
// atomically accumulated into sumexp[]; diag masked; pos captured (rows<4096).
__global__ __launch_bounds__(256, 2) void k_simloss(const unsigned short* __restrict__ z,
                                                    float* __restrict__ sumexp,
                                                    float* __restrict__ pos) {
    __shared__ unsigned short lds[COLS_PER_ITER * LDS_STRIDE];  // 17408 B

    const int tid  = threadIdx.x;
    const int wave = tid >> 6;
    const int lane = tid & 63;
    const int l15  = lane & 15;
    const int quad = lane >> 4;

    // Decode triangle block: (bi row-strip of 256, jh col-pair of 128), jh >= 2*bi.
    int b = blockIdx.x, bi = 0;
    while (b >= 64 - 2 * bi) { b -= 64 - 2 * bi; ++bi; }
    const int jh = 2 * bi + b;
    const int wrow = bi * 256 + wave * 64;
    const int colbase0 = jh * 128;

    // A fragments: 4 row-stripes of 16 x K=128, register-resident (64 VGPRs).
    frag8 a[4][4];
    #pragma unroll
    for (int s = 0; s < 4; ++s) {
        const uint4* p = (const uint4*)&z[(wrow + s * 16 + l15) * D + quad * 8];
        #pragma unroll
        for (int q = 0; q < 4; ++q) {
            uint4 t = p[q * 4];
            a[s][q] = *(frag8*)&t;
        }
    }

    float sums[4][4];
    #pragma unroll
    for (int s = 0; s < 4; ++s)
        #pragma unroll
        for (int r = 0; r < 4; ++r) sums[s][r] = 0.0f;

    for (int it = 0; it < ITERS; ++it) {
        const int colbase = colbase0 + it * COLS_PER_ITER;
        __syncthreads();
        #pragma unroll
        for (int u = 0; u < 4; ++u) {
            int idx = u * 256 + tid;
            int r   = idx >> 4;
            int c8  = idx & 15;
            uint4 t = *(const uint4*)&z[(colbase + r) * D + c8 * 8];
            *(uint4*)&lds[r * LDS_STRIDE + c8 * 8] = t;
        }
        __syncthreads();

        const bool active = (colbase >= wrow);        // strictly-lower tiles skipped
        const bool isSelf = (colbase == wrow);        // on-diagonal tile: no mirror
        const bool isPos  = (colbase == wrow + HALF_N);
        if (!active) continue;  // barriers already passed; safe (uniform per wave)

        const unsigned short* lp = &lds[l15 * LDS_STRIDE + quad * 8];

        #pragma unroll
        for (int c = 0; c < 4; ++c) {
            f32x4 acc[4];
            #pragma unroll
            for (int s = 0; s < 4; ++s) acc[s] = (f32x4){0.f, 0.f, 0.f, 0.f};
            #pragma unroll
            for (int q = 0; q < 4; ++q) {
                frag8 bf = *(const frag8*)(lp + c * 16 * LDS_STRIDE + q * 32);
                #pragma unroll
                for (int s = 0; s < 4; ++s)
                    acc[s] = __builtin_amdgcn_mfma_f32_16x16x32_bf16(a[s][q], bf, acc[s], 0, 0, 0);
            }
            float cs = 0.0f;  // column partial (mirror contribution)
            if (isSelf | isPos) {
                // special tile: local diagonal element at c==s, l15==quad*4+r
                #pragma unroll
                for (int s = 0; s < 4; ++s)
                    #pragma unroll
                    for (int r = 0; r < 4; ++r) {
                        float v = acc[s][r];
                        float e = __builtin_amdgcn_exp2f(v);
                        if (c == s) {  // compile-time
                            bool hit = (l15 == quad * 4 + r);
                            if (isSelf && hit) e = 0.0f;
                            if (isPos  && hit) pos[wrow + s * 16 + quad * 4 + r] = v * LN2;
                        }
                        sums[s][r] += e;
                        cs += e;
                    }
            } else {
                #pragma unroll
                for (int s = 0; s < 4; ++s)
                    #pragma unroll
                    for (int r = 0; r < 4; ++r) {
                        float e = __builtin_amdgcn_exp2f(acc[s][r]);
                        sums[s][r] += e;
                        cs += e;
                    }
            }
            if (!isSelf) {
                // reduce over quads -> col-sum for column colbase + c*16 + l15
                cs += __shfl_xor(cs, 16);
                cs += __shfl_xor(cs, 32);
                if (quad == 0)
                    atomicAdd(&sumexp[colbase + c * 16 + l15], cs);
            }
        }
    }

    // Row-sums: reduce across the 16 lanes holding each row, one atomic per row.
    #pragma unroll
    for (int s = 0; s < 4; ++s)
        #pragma unroll
        for (int r = 0; r < 4; ++r) {
            float v = sums[s][r];
            v += __shfl_xor(v, 1);
            v += __shfl_xor(v, 2);
            v += __shfl_xor(v, 4);
            v += __shfl_xor(v, 8);
            if (l15 == 0)
                atomicAdd(&sumexp[wrow + s * 16 + quad * 4 + r], v);
        }
}

// K3: per-row loss = log(sumexp) - pos (pos mirrored for rows >= N/2);
// block-reduce; last block writes the mean.
__global__ __launch_bounds__(256) void k_rowloss(const float* __restrict__ sumexp,
                                                 const float* __restrict__ pos,
                                                 float* __restrict__ acc0,
                                                 unsigned int* __restrict__ counter,
                                                 float* __restrict__ out) {
    const int row = blockIdx.x * 256 + threadIdx.x;
    float loss = __logf(sumexp[row]) - pos[row & (HALF_N - 1)];
    #pragma unroll
    for (int m = 32; m >= 1; m >>= 1) loss += __shfl_xor(loss, m);
    __shared__ float p[4];
    if ((threadIdx.x & 63) == 0) p[threadIdx.x >> 6] = loss;
    __syncthreads();
    if (threadIdx.x == 0) {
        atomicAdd(acc0, p[0] + p[1] + p[2] + p[3]);
        __threadfence();
        unsigned prev = atomicAdd(counter, 1u);
        if (prev == gridDim.x - 1) {
            float total = atomicAdd(acc0, 0.0f);  // coherent read-back
            out[0] = total * (1.0f / N);
        }
    }
}

extern "C" void kernel_launch(void* const* d_in, const int* in_sizes, int n_in,
                              void* d_out, int out_size, void* d_ws, size_t ws_size,
                              hipStream_t stream) {
    const float* x = (const float*)d_in[0];
    float* wsf    = (float*)d_ws;
    float* pos    = wsf + OFF_POS;
    float* sumexp = wsf + OFF_SUM;
    float* acc0   = wsf + OFF_ACC;
    unsigned int* counter = (unsigned int*)(wsf + OFF_CNT);
    unsigned short* z = (unsigned short*)((char*)d_ws + OFF_Z_BYTES);

    k_normalize<<<N / 4, 256, 0, stream>>>(x, z, wsf);
    k_simloss<<<1056, 256, 0, stream>>>(z, sumexp, pos);  // 33*64/2 triangle blocks
    k_rowloss<<<N / 256, 256, 0, stream>>>(sumexp, pos, acc0, counter, (float*)d_out);
}